// Round 2
// 996.762 us; speedup vs baseline: 1.0192x; 1.0192x over previous
//
#include <hip/hip_runtime.h>
#include <math.h>

#define NB 4        // batch pairs
#define N 4096      // points
#define CF 640      // feature dim

typedef _Float16 f16;
typedef _Float16 f16x8 __attribute__((ext_vector_type(8)));
typedef _Float16 f16x4 __attribute__((ext_vector_type(4)));
typedef float    f32x4 __attribute__((ext_vector_type(4)));
typedef unsigned int u32;

// ---------------- workspace layout (byte offsets) ----------------
// fnT  : 8*N*CF fp16 (normalized features, (b,n,c))
// rnorm: 8*N float  (aliased as rowsum later)
// bvec : NB*N float
// Kh   : NB*N*N fp16 (fp16 shadow of K for Sinkhorn)
// ktap : NB*64*N f32 (column-sum partials)
// fp32 K itself lives in d_out's T region (finalized in place).
#define OFF_FNT   0ll
#define OFF_RNORM (OFF_FNT + 8ll*N*CF*2)
#define OFF_BVEC  (OFF_RNORM + 8ll*N*4)
#define OFF_SCR   (OFF_BVEC + (long long)NB*N*4)
#define OFF_KTAP  (OFF_SCR + (long long)NB*N*N*2)
#define REQ_H     (OFF_KTAP + (long long)NB*64*N*4)
#define REQ_F     (OFF_SCR + (long long)NB*64*N*4)

__device__ inline void async_copy16(void* lds, const void* g) {
    __builtin_amdgcn_global_load_lds(
        (const __attribute__((address_space(1))) u32*)g,
        (__attribute__((address_space(3))) u32*)lds,
        16, 0, 0);
}

// ---------------- pass 1: per-point inverse norms ----------------
__global__ __launch_bounds__(256) void rnorm_kernel(const float* __restrict__ pf,
                                                    float* __restrict__ rnorm) {
    int idx = blockIdx.x * 256 + threadIdx.x;   // over 8*4096
    int n = idx & (N - 1);
    int b = idx >> 12;
    const float* src = pf + (size_t)b * CF * N + n;
    float s = 0.f;
    for (int c = 0; c < CF; ++c) { float v = src[(size_t)c * N]; s = fmaf(v, v, s); }
    rnorm[idx] = 1.0f / sqrtf(s + 1e-8f);
}

// ---------------- pass 2: transpose (c,n)->(n,c), scale, fp16 ----------------
__global__ __launch_bounds__(256) void transpose_kernel(const float* __restrict__ pf,
                                                        const float* __restrict__ rnorm,
                                                        f16* __restrict__ fnT) {
    __shared__ float tile[64][65];
    int b  = blockIdx.z;
    int c0 = blockIdx.x * 64;
    int n1 = blockIdx.y * 64;
    int t  = threadIdx.x;

    int c_l = t >> 4;               // 0..15
    int n_l4 = (t & 15) * 4;        // 0..60
    #pragma unroll
    for (int i = 0; i < 4; ++i) {
        int c = c_l + i * 16;
        float4 v = *(const float4*)(pf + (size_t)(b * CF + c0 + c) * N + n1 + n_l4);
        tile[c][n_l4 + 0] = v.x; tile[c][n_l4 + 1] = v.y;
        tile[c][n_l4 + 2] = v.z; tile[c][n_l4 + 3] = v.w;
    }
    __syncthreads();

    int n_l = t >> 2;               // 0..63
    int c_g = (t & 3) * 16;         // 0,16,32,48
    float rn = rnorm[b * N + n1 + n_l];
    f16 tmp[16] __attribute__((aligned(16)));
    #pragma unroll
    for (int i = 0; i < 16; ++i)
        tmp[i] = (f16)(tile[c_g + i][n_l] * rn);
    f16* dst = fnT + (size_t)(b * N + n1 + n_l) * CF + c0 + c_g;
    ((uint4*)dst)[0] = ((const uint4*)tmp)[0];
    ((uint4*)dst)[1] = ((const uint4*)tmp)[1];
}

// ---------------- MFMA GEMM: K = exp((f1 f2^T - 1)/eps) ----------------
// Writes fp32 K (scattered, into d_out T region) for the accurate final pass,
// plus (H path) a coalesced fp16 shadow Kh via LDS transpose, plus per-block
// column-sum partials (= N * (K^T a0)) into ktap[b][blockIdx.x][...].
template<bool H>
__global__ __launch_bounds__(256) void gemm_k(const f16* __restrict__ fnT,
                                              const float* __restrict__ e_in,
                                              float* __restrict__ Kf,
                                              f16* __restrict__ Kh,
                                              float* __restrict__ ktap) {
    int b  = blockIdx.z;
    int m0 = blockIdx.y * 128;
    int n0 = blockIdx.x * 128;
    const f16* A = fnT + (size_t)b       * N * CF;   // rows n
    const f16* B = fnT + (size_t)(b + 4) * N * CF;   // rows m

    __shared__ f16 As[128 * 32];
    __shared__ f16 Bs[128 * 32];
    __shared__ float cs[2][128];
    __shared__ f16 Ct[H ? 128 * 136 : 1];   // stride 136: 16B-aligned rows

    int tid = threadIdx.x;
    int w = tid >> 6;        // wave 0..3
    int l = tid & 63;        // lane
    int wr = w >> 1, wc = w & 1;

    f32x4 acc[4][4];
    #pragma unroll
    for (int i = 0; i < 4; ++i)
        #pragma unroll
        for (int j = 0; j < 4; ++j)
            acc[i][j] = (f32x4){0.f, 0.f, 0.f, 0.f};

    int srow = l >> 2;       // 0..15 within chunk
    int scp  = l & 3;        // stored chunk index c'

    for (int c0 = 0; c0 < CF; c0 += 32) {
        #pragma unroll
        for (int q = 0; q < 2; ++q) {
            int ch = w * 2 + q;          // 0..7
            int row = ch * 16 + srow;    // 0..127
            int cc = scp ^ ((row >> 1) & 3);
            async_copy16(&As[ch * 512], A + (size_t)(n0 + row) * CF + c0 + cc * 8);
            async_copy16(&Bs[ch * 512], B + (size_t)(m0 + row) * CF + c0 + cc * 8);
        }
        __syncthreads();

        f16x8 af[4], bfr[4];
        int g = l >> 4, low = l & 15;
        #pragma unroll
        for (int t = 0; t < 4; ++t) {
            int rowA = wr * 64 + t * 16 + low;
            af[t] = *(const f16x8*)(As + rowA * 32 + (g ^ ((rowA >> 1) & 3)) * 8);
            int rowB = wc * 64 + t * 16 + low;
            bfr[t] = *(const f16x8*)(Bs + rowB * 32 + (g ^ ((rowB >> 1) & 3)) * 8);
        }
        #pragma unroll
        for (int i = 0; i < 4; ++i)
            #pragma unroll
            for (int j = 0; j < 4; ++j)
                acc[i][j] = __builtin_amdgcn_mfma_f32_16x16x32_f16(af[i], bfr[j], acc[i][j], 0, 0, 0);
        __syncthreads();
    }

    float eps = expf(e_in[0]) + 0.03f;
    float inv_eps = 1.0f / eps;
    int g4 = l >> 4, low = l & 15;
    float colp[4] = {0.f, 0.f, 0.f, 0.f};
    float* out = Kf + (size_t)b * N * N;

    #pragma unroll
    for (int i = 0; i < 4; ++i) {
        int rl = wr * 64 + i * 16 + g4 * 4;
        #pragma unroll
        for (int j = 0; j < 4; ++j) {
            int cl = wc * 64 + j * 16 + low;
            #pragma unroll
            for (int r = 0; r < 4; ++r) {
                float v = expf((acc[i][j][r] - 1.0f) * inv_eps);
                out[(size_t)(n0 + rl + r) * N + m0 + cl] = v;
                if constexpr (H) Ct[(rl + r) * 136 + cl] = (f16)v;
                colp[j] += v;
            }
        }
    }

    // reduce column partials across g (lanes l, l+16, l+32, l+48 share a column)
    #pragma unroll
    for (int j = 0; j < 4; ++j) {
        float c = colp[j];
        c += __shfl_down(c, 32);
        c += __shfl_down(c, 16);
        if (l < 16) cs[wr][wc * 64 + j * 16 + l] = c;
    }
    __syncthreads();
    if (tid < 128)
        ktap[((size_t)b * 64 + blockIdx.x) * N + m0 + tid] =
            (cs[0][tid] + cs[1][tid]) * (1.0f / N);

    if constexpr (H) {
        f16* oh = Kh + (size_t)b * N * N;
        int row0 = tid >> 4, c8 = (tid & 15) * 8;
        #pragma unroll
        for (int rr = 0; rr < 8; ++rr) {
            int row = rr * 16 + row0;
            f16x8 v = *(const f16x8*)(Ct + row * 136 + c8);
            *(f16x8*)(oh + (size_t)(n0 + row) * N + m0 + c8) = v;
        }
    }
}

// ---------------- b[m] = (prob2/(KTa[m]+1e-8))^power, KTa from npart partials ----
__global__ __launch_bounds__(256) void bvec_kernel(const float* __restrict__ ktap, int npart,
                                                   const float* __restrict__ g_in,
                                                   const float* __restrict__ e_in,
                                                   float* __restrict__ bvec) {
    int i = blockIdx.x * 256 + threadIdx.x;   // NB*N total
    int b = i >> 12, m = i & (N - 1);
    const float* p = ktap + (size_t)b * 64 * N + m;
    float s = 0.f;
    for (int k = 0; k < npart; ++k) s += p[(size_t)k * N];
    float eps = expf(e_in[0]) + 0.03f;
    float gam = expf(g_in[0]);
    float power = gam / (gam + eps);
    bvec[i] = powf((1.0f / N) / (s + 1e-8f), power);
}

// ---------------- fused: Kb -> a (in-block), then partial K^T a  ----------------
// One HBM pass over K per Sinkhorn iteration instead of two.
// Grid (64 slabs of 64 rows, NB). Phase 2 re-reads the slab (L2-hot, 512 KB).
template<bool H>
__global__ __launch_bounds__(256) void fused_iter(const void* __restrict__ Kp,
                                                  const float* __restrict__ bv_in,
                                                  const float* __restrict__ g_in,
                                                  const float* __restrict__ e_in,
                                                  float* __restrict__ ktap) {
    int b = blockIdx.y, slab = blockIdx.x;
    int n0s = slab * 64;
    int w = threadIdx.x >> 6, l = threadIdx.x & 63;
    __shared__ float ash[64];
    float eps = expf(e_in[0]) + 0.03f;
    float gam = expf(g_in[0]);
    float power = gam / (gam + eps);
    const float* bv = bv_in + b * N;

    float acc[16];
    #pragma unroll
    for (int q = 0; q < 16; ++q) acc[q] = 0.f;

    // phase 1: wave w handles rows rr*4+w; per column chunk, b in registers
    if constexpr (H) {
        const f16* Kb = (const f16*)Kp + ((size_t)b * N + n0s) * N;
        for (int it = 0; it < 8; ++it) {
            int m = it * 512 + l * 8;
            float bq[8];
            *(float4*)&bq[0] = *(const float4*)(bv + m);
            *(float4*)&bq[4] = *(const float4*)(bv + m + 4);
            #pragma unroll
            for (int rr = 0; rr < 16; ++rr) {
                f16x8 v = *(const f16x8*)(Kb + (size_t)(rr * 4 + w) * N + m);
                #pragma unroll
                for (int q = 0; q < 8; ++q) acc[rr] = fmaf((float)v[q], bq[q], acc[rr]);
            }
        }
    } else {
        const float* Kb = (const float*)Kp + ((size_t)b * N + n0s) * N;
        for (int it = 0; it < 16; ++it) {
            int m = it * 256 + l * 4;
            float4 bq = *(const float4*)(bv + m);
            #pragma unroll
            for (int rr = 0; rr < 16; ++rr) {
                float4 v = *(const float4*)(Kb + (size_t)(rr * 4 + w) * N + m);
                acc[rr] = fmaf(v.x, bq.x, acc[rr]);
                acc[rr] = fmaf(v.y, bq.y, acc[rr]);
                acc[rr] = fmaf(v.z, bq.z, acc[rr]);
                acc[rr] = fmaf(v.w, bq.w, acc[rr]);
            }
        }
    }
    #pragma unroll
    for (int rr = 0; rr < 16; ++rr) {
        float s = acc[rr];
        s += __shfl_down(s, 32);
        s += __shfl_down(s, 16);
        s += __shfl_down(s, 8);
        s += __shfl_down(s, 4);
        s += __shfl_down(s, 2);
        s += __shfl_down(s, 1);
        if (l == 0) ash[rr * 4 + w] = powf((1.0f / N) / (s + 1e-8f), power);
    }
    __syncthreads();

    // phase 2: partial K^T a over this slab; thread owns cols {t*4+j + q*1024}
    float cacc[16];
    #pragma unroll
    for (int q = 0; q < 16; ++q) cacc[q] = 0.f;
    int t4 = threadIdx.x * 4;
    if constexpr (H) {
        const f16* Kb = (const f16*)Kp + ((size_t)b * N + n0s) * N;
        for (int r = 0; r < 64; ++r) {
            float a = ash[r];
            #pragma unroll
            for (int q = 0; q < 4; ++q) {
                f16x4 v = *(const f16x4*)(Kb + (size_t)r * N + q * 1024 + t4);
                #pragma unroll
                for (int j = 0; j < 4; ++j)
                    cacc[q * 4 + j] = fmaf((float)v[j], a, cacc[q * 4 + j]);
            }
        }
    } else {
        const float* Kb = (const float*)Kp + ((size_t)b * N + n0s) * N;
        for (int r = 0; r < 64; ++r) {
            float a = ash[r];
            #pragma unroll
            for (int q = 0; q < 4; ++q) {
                float4 v = *(const float4*)(Kb + (size_t)r * N + q * 1024 + t4);
                cacc[q * 4 + 0] = fmaf(v.x, a, cacc[q * 4 + 0]);
                cacc[q * 4 + 1] = fmaf(v.y, a, cacc[q * 4 + 1]);
                cacc[q * 4 + 2] = fmaf(v.z, a, cacc[q * 4 + 2]);
                cacc[q * 4 + 3] = fmaf(v.w, a, cacc[q * 4 + 3]);
            }
        }
    }
    float* o = ktap + ((size_t)b * 64 + slab) * N;
    #pragma unroll
    for (int q = 0; q < 4; ++q)
        *(float4*)(o + q * 1024 + t4) =
            make_float4(cacc[q * 4], cacc[q * 4 + 1], cacc[q * 4 + 2], cacc[q * 4 + 3]);
}

// ---------------- final: a5 = g(K b5) in-block from fp32 K; T = a K b^T in place ----
__global__ __launch_bounds__(256) void final_k(float* __restrict__ Tout,
                                               const float* __restrict__ bv_in,
                                               const float* __restrict__ g_in,
                                               const float* __restrict__ e_in,
                                               const float* __restrict__ pc,
                                               float* __restrict__ rowsum,
                                               float* __restrict__ matches) {
    int b = blockIdx.y, n = blockIdx.x;
    int t = threadIdx.x;
    int t4 = t * 4;
    const float* bv = bv_in + b * N;
    float kv[16], bl[16];
    float* Trow = Tout + ((size_t)b * N + n) * N;
    #pragma unroll
    for (int q = 0; q < 4; ++q) {
        *(float4*)&bl[q * 4] = *(const float4*)(bv + q * 1024 + t4);
        *(float4*)&kv[q * 4] = *(const float4*)(Trow + q * 1024 + t4);
    }
    float s = 0.f;
    #pragma unroll
    for (int q = 0; q < 16; ++q) s = fmaf(kv[q], bl[q], s);
    __shared__ float red[256];
    red[t] = s; __syncthreads();
    for (int off = 128; off; off >>= 1) {
        if (t < off) red[t] += red[t + off];
        __syncthreads();
    }
    __shared__ float a_sh;
    if (t == 0) {
        float eps = expf(e_in[0]) + 0.03f;
        float gam = expf(g_in[0]);
        float power = gam / (gam + eps);
        a_sh = powf((1.0f / N) / (red[0] + 1e-8f), power);
    }
    __syncthreads();
    float an = a_sh;
    const float4* c2 = (const float4*)pc + (size_t)(4 + b) * N;
    float rs = 0.f, s0 = 0.f, s1 = 0.f, s2 = 0.f;
    #pragma unroll
    for (int q = 0; q < 4; ++q) {
        float tv0 = an * kv[q * 4 + 0] * bl[q * 4 + 0];
        float tv1 = an * kv[q * 4 + 1] * bl[q * 4 + 1];
        float tv2 = an * kv[q * 4 + 2] * bl[q * 4 + 2];
        float tv3 = an * kv[q * 4 + 3] * bl[q * 4 + 3];
        *(float4*)(Trow + q * 1024 + t4) = make_float4(tv0, tv1, tv2, tv3);
        rs += tv0 + tv1 + tv2 + tv3;
        float4 c0 = c2[q * 1024 + t4],     c1 = c2[q * 1024 + t4 + 1],
               cc = c2[q * 1024 + t4 + 2], c3 = c2[q * 1024 + t4 + 3];
        s0 = fmaf(tv0, c0.y, s0); s1 = fmaf(tv0, c0.z, s1); s2 = fmaf(tv0, c0.w, s2);
        s0 = fmaf(tv1, c1.y, s0); s1 = fmaf(tv1, c1.z, s1); s2 = fmaf(tv1, c1.w, s2);
        s0 = fmaf(tv2, cc.y, s0); s1 = fmaf(tv2, cc.z, s1); s2 = fmaf(tv2, cc.w, s2);
        s0 = fmaf(tv3, c3.y, s0); s1 = fmaf(tv3, c3.z, s1); s2 = fmaf(tv3, c3.w, s2);
    }
    __shared__ float4 red4[256];
    red4[t] = make_float4(rs, s0, s1, s2); __syncthreads();
    for (int off = 128; off; off >>= 1) {
        if (t < off) {
            float4 o = red4[t + off];
            red4[t].x += o.x; red4[t].y += o.y; red4[t].z += o.z; red4[t].w += o.w;
        }
        __syncthreads();
    }
    if (t == 0) {
        float4 tot = red4[0];
        rowsum[b * N + n] = tot.x;
        float inv = 1.0f / (tot.x + 1e-8f);
        float* mo = matches + ((size_t)b * N + n) * 3;
        mo[0] = tot.y * inv; mo[1] = tot.z * inv; mo[2] = tot.w * inv;
    }
}

// ---------------- weighted Kabsch with 3x3 SVD (fp64) ----------------
__global__ __launch_bounds__(256) void transform_kernel(const float* __restrict__ rowsum,
                                                        const float* __restrict__ matches,
                                                        const float* __restrict__ pc,
                                                        float* __restrict__ out) {
    int b = blockIdx.x;
    float vals[16];
    #pragma unroll
    for (int q = 0; q < 16; ++q) vals[q] = 0.f;
    for (int n = threadIdx.x; n < N; n += 256) {
        float w = rowsum[b * N + n];
        float4 c1 = ((const float4*)pc)[(size_t)b * N + n];
        float ax = c1.y, ay = c1.z, az = c1.w;
        const float* mm = matches + ((size_t)b * N + n) * 3;
        float bx = mm[0], by = mm[1], bz = mm[2];
        vals[0] += w;
        vals[1] = fmaf(w, ax, vals[1]); vals[2] = fmaf(w, ay, vals[2]); vals[3] = fmaf(w, az, vals[3]);
        vals[4] = fmaf(w, bx, vals[4]); vals[5] = fmaf(w, by, vals[5]); vals[6] = fmaf(w, bz, vals[6]);
        vals[7]  = fmaf(w * ax, bx, vals[7]);  vals[8]  = fmaf(w * ax, by, vals[8]);  vals[9]  = fmaf(w * ax, bz, vals[9]);
        vals[10] = fmaf(w * ay, bx, vals[10]); vals[11] = fmaf(w * ay, by, vals[11]); vals[12] = fmaf(w * ay, bz, vals[12]);
        vals[13] = fmaf(w * az, bx, vals[13]); vals[14] = fmaf(w * az, by, vals[14]); vals[15] = fmaf(w * az, bz, vals[15]);
    }
    __shared__ float red[256];
    __shared__ float tot[16];
    for (int q = 0; q < 16; ++q) {
        red[threadIdx.x] = vals[q]; __syncthreads();
        for (int off = 128; off; off >>= 1) {
            if (threadIdx.x < off) red[threadIdx.x] += red[threadIdx.x + off];
            __syncthreads();
        }
        if (threadIdx.x == 0) tot[q] = red[0];
        __syncthreads();
    }
    if (threadIdx.x != 0) return;

    double S = tot[0];
    double denom = S + 1e-5;
    double Ca[3], Cb[3], M[3][3], cov[3][3];
    for (int i = 0; i < 3; ++i) { Ca[i] = tot[1 + i] / denom; Cb[i] = tot[4 + i] / denom; }
    for (int i = 0; i < 3; ++i)
        for (int j = 0; j < 3; ++j)
            M[i][j] = tot[7 + i * 3 + j] / denom;
    double s0 = S / denom;
    for (int i = 0; i < 3; ++i)
        for (int j = 0; j < 3; ++j)
            cov[i][j] = M[i][j] - Ca[i] * Cb[j] * (2.0 - s0);

    double Sm[3][3], V[3][3] = {{1,0,0},{0,1,0},{0,0,1}};
    for (int i = 0; i < 3; ++i)
        for (int j = 0; j < 3; ++j) {
            double acc = 0;
            for (int k = 0; k < 3; ++k) acc += cov[k][i] * cov[k][j];
            Sm[i][j] = acc;
        }
    for (int sweep = 0; sweep < 20; ++sweep) {
        static const int pq[3][2] = {{0,1},{0,2},{1,2}};
        for (int r = 0; r < 3; ++r) {
            int p = pq[r][0], q = pq[r][1];
            double apq = Sm[p][q];
            if (fabs(apq) < 1e-30) continue;
            double tau = (Sm[q][q] - Sm[p][p]) / (2.0 * apq);
            double t = (tau >= 0) ? 1.0 / (tau + sqrt(1.0 + tau * tau))
                                  : 1.0 / (tau - sqrt(1.0 + tau * tau));
            double c = 1.0 / sqrt(1.0 + t * t), s = t * c;
            for (int i = 0; i < 3; ++i) {
                double sip = Sm[i][p], siq = Sm[i][q];
                Sm[i][p] = c * sip - s * siq; Sm[i][q] = s * sip + c * siq;
            }
            for (int j = 0; j < 3; ++j) {
                double spj = Sm[p][j], sqj = Sm[q][j];
                Sm[p][j] = c * spj - s * sqj; Sm[q][j] = s * spj + c * sqj;
            }
            for (int i = 0; i < 3; ++i) {
                double vip = V[i][p], viq = V[i][q];
                V[i][p] = c * vip - s * viq; V[i][q] = s * vip + c * viq;
            }
        }
    }
    double lam[3] = {Sm[0][0], Sm[1][1], Sm[2][2]};
    for (int i = 0; i < 2; ++i)
        for (int j = i + 1; j < 3; ++j)
            if (lam[j] > lam[i]) {
                double tl = lam[i]; lam[i] = lam[j]; lam[j] = tl;
                for (int k = 0; k < 3; ++k) { double tv = V[k][i]; V[k][i] = V[k][j]; V[k][j] = tv; }
            }
    double U[3][3];
    double sig0 = sqrt(fmax(lam[0], 0.0));
    for (int j = 0; j < 3; ++j) {
        double sig = sqrt(fmax(lam[j], 0.0));
        if (sig > 1e-12 * (sig0 + 1e-300)) {
            double nrm = 0;
            for (int i = 0; i < 3; ++i) {
                double u = cov[i][0] * V[0][j] + cov[i][1] * V[1][j] + cov[i][2] * V[2][j];
                U[i][j] = u; nrm += u * u;
            }
            nrm = 1.0 / sqrt(nrm + 1e-300);
            for (int i = 0; i < 3; ++i) U[i][j] *= nrm;
        } else {
            U[0][j] = U[1][0] * U[2][1] - U[2][0] * U[1][1];
            U[1][j] = U[2][0] * U[0][1] - U[0][0] * U[2][1];
            U[2][j] = U[0][0] * U[1][1] - U[1][0] * U[0][1];
        }
    }
    double R[3][3];
    for (int i = 0; i < 3; ++i)
        for (int j = 0; j < 3; ++j)
            R[i][j] = V[i][0] * U[j][0] + V[i][1] * U[j][1] + V[i][2] * U[j][2];
    double det = R[0][0] * (R[1][1] * R[2][2] - R[1][2] * R[2][1])
               - R[0][1] * (R[1][0] * R[2][2] - R[1][2] * R[2][0])
               + R[0][2] * (R[1][0] * R[2][1] - R[1][1] * R[2][0]);
    if (!(det > 0)) {
        for (int k = 0; k < 3; ++k) V[k][2] = -V[k][2];
        for (int i = 0; i < 3; ++i)
            for (int j = 0; j < 3; ++j)
                R[i][j] = V[i][0] * U[j][0] + V[i][1] * U[j][1] + V[i][2] * U[j][2];
    }
    double tr[3];
    for (int i = 0; i < 3; ++i)
        tr[i] = -(R[i][0] * Ca[0] + R[i][1] * Ca[1] + R[i][2] * Ca[2]) + Cb[i];
    float* o = out + b * 12;
    for (int i = 0; i < 3; ++i) {
        o[i * 4 + 0] = (float)R[i][0];
        o[i * 4 + 1] = (float)R[i][1];
        o[i * 4 + 2] = (float)R[i][2];
        o[i * 4 + 3] = (float)tr[i];
    }
}

extern "C" void kernel_launch(void* const* d_in, const int* in_sizes, int n_in,
                              void* d_out, int out_size, void* d_ws, size_t ws_size,
                              hipStream_t stream) {
    const float* pf   = (const float*)d_in[0];
    const float* pc   = (const float*)d_in[1];
    const float* g_in = (const float*)d_in[2];
    const float* e_in = (const float*)d_in[3];

    char* wsb = (char*)d_ws;
    f16*   fnT   = (f16*)(wsb + OFF_FNT);
    float* rnorm = (float*)(wsb + OFF_RNORM);
    float* bvec  = (float*)(wsb + OFF_BVEC);

    float* T_out   = (float*)d_out;
    float* matches = T_out + (size_t)NB * N * N;
    float* trans   = matches + (size_t)NB * N * 3;
    // rnorm consumed by transpose_kernel before final_k runs -> safe alias
    float* rowsum  = rnorm;

    rnorm_kernel<<<dim3(8 * N / 256), 256, 0, stream>>>(pf, rnorm);
    transpose_kernel<<<dim3(CF / 64, N / 64, 8), 256, 0, stream>>>(pf, rnorm, fnT);

    if (ws_size >= (size_t)REQ_H) {
        // fp32 K in d_out T region (for accurate final), fp16 shadow for Sinkhorn.
        f16*   Kh   = (f16*)(wsb + OFF_SCR);
        float* ktap = (float*)(wsb + OFF_KTAP);
        gemm_k<true><<<dim3(N / 128, N / 128, NB), 256, 0, stream>>>(fnT, e_in, T_out, Kh, ktap);
        bvec_kernel<<<dim3(NB * N / 256), 256, 0, stream>>>(ktap, 32, g_in, e_in, bvec);
        for (int it = 0; it < 4; ++it) {
            fused_iter<true><<<dim3(64, NB), 256, 0, stream>>>(Kh, bvec, g_in, e_in, ktap);
            bvec_kernel<<<dim3(NB * N / 256), 256, 0, stream>>>(ktap, 64, g_in, e_in, bvec);
        }
        final_k<<<dim3(N, NB), 256, 0, stream>>>(T_out, bvec, g_in, e_in, pc, rowsum, matches);
    } else {
        // fallback: fp32 K everywhere (Sinkhorn reads fp32 K from T region)
        float* ktap = (float*)(wsb + OFF_SCR);
        gemm_k<false><<<dim3(N / 128, N / 128, NB), 256, 0, stream>>>(fnT, e_in, T_out, (f16*)nullptr, ktap);
        bvec_kernel<<<dim3(NB * N / 256), 256, 0, stream>>>(ktap, 32, g_in, e_in, bvec);
        for (int it = 0; it < 4; ++it) {
            fused_iter<false><<<dim3(64, NB), 256, 0, stream>>>(T_out, bvec, g_in, e_in, ktap);
            bvec_kernel<<<dim3(NB * N / 256), 256, 0, stream>>>(ktap, 64, g_in, e_in, bvec);
        }
        final_k<<<dim3(N, NB), 256, 0, stream>>>(T_out, bvec, g_in, e_in, pc, rowsum, matches);
    }

    transform_kernel<<<dim3(NB), 256, 0, stream>>>(rowsum, matches, pc, trans);
}

// Round 3
// 867.591 us; speedup vs baseline: 1.1709x; 1.1489x over previous
//
#include <hip/hip_runtime.h>
#include <math.h>

#define NB 4        // batch pairs
#define N 4096      // points
#define CF 640      // feature dim

typedef _Float16 f16;
typedef _Float16 f16x8 __attribute__((ext_vector_type(8)));
typedef _Float16 f16x4 __attribute__((ext_vector_type(4)));
typedef float    f32x4 __attribute__((ext_vector_type(4)));
typedef unsigned int u32;

// ---------------- workspace layout (byte offsets) ----------------
// fnT  : 8*N*CF fp16 (normalized features, (b,n,c)); DEAD after gemm_k ->
//        reused as ktapF (NB*256*N f32 = 16.8MB <= 41.9MB) by fused_iter.
// rnorm: 8*N float  (aliased as rowsum later)
// bvec : NB*N float
// Kh   : NB*N*N fp16 (fp16 shadow of K for Sinkhorn)
// ktapG: NB*64*N f32 (gemm-folded first column-sum partials, 32 slots used)
// fp32 K itself lives in d_out's T region (finalized in place).
#define OFF_FNT   0ll
#define OFF_RNORM (OFF_FNT + 8ll*N*CF*2)
#define OFF_BVEC  (OFF_RNORM + 8ll*N*4)
#define OFF_SCR   (OFF_BVEC + (long long)NB*N*4)
#define OFF_KTAP  (OFF_SCR + (long long)NB*N*N*2)
#define REQ_H     (OFF_KTAP + (long long)NB*64*N*4)
#define REQ_F     (OFF_SCR + (long long)NB*64*N*4)

__device__ inline void async_copy16(void* lds, const void* g) {
    __builtin_amdgcn_global_load_lds(
        (const __attribute__((address_space(1))) u32*)g,
        (__attribute__((address_space(3))) u32*)lds,
        16, 0, 0);
}

// ---------------- pass 1: per-point inverse norms ----------------
__global__ __launch_bounds__(256) void rnorm_kernel(const float* __restrict__ pf,
                                                    float* __restrict__ rnorm) {
    int idx = blockIdx.x * 256 + threadIdx.x;   // over 8*4096
    int n = idx & (N - 1);
    int b = idx >> 12;
    const float* src = pf + (size_t)b * CF * N + n;
    float s = 0.f;
    for (int c = 0; c < CF; ++c) { float v = src[(size_t)c * N]; s = fmaf(v, v, s); }
    rnorm[idx] = 1.0f / sqrtf(s + 1e-8f);
}

// ---------------- pass 2: transpose (c,n)->(n,c), scale, fp16 ----------------
__global__ __launch_bounds__(256) void transpose_kernel(const float* __restrict__ pf,
                                                        const float* __restrict__ rnorm,
                                                        f16* __restrict__ fnT) {
    __shared__ float tile[64][65];
    int b  = blockIdx.z;
    int c0 = blockIdx.x * 64;
    int n1 = blockIdx.y * 64;
    int t  = threadIdx.x;

    int c_l = t >> 4;               // 0..15
    int n_l4 = (t & 15) * 4;        // 0..60
    #pragma unroll
    for (int i = 0; i < 4; ++i) {
        int c = c_l + i * 16;
        float4 v = *(const float4*)(pf + (size_t)(b * CF + c0 + c) * N + n1 + n_l4);
        tile[c][n_l4 + 0] = v.x; tile[c][n_l4 + 1] = v.y;
        tile[c][n_l4 + 2] = v.z; tile[c][n_l4 + 3] = v.w;
    }
    __syncthreads();

    int n_l = t >> 2;               // 0..63
    int c_g = (t & 3) * 16;         // 0,16,32,48
    float rn = rnorm[b * N + n1 + n_l];
    f16 tmp[16] __attribute__((aligned(16)));
    #pragma unroll
    for (int i = 0; i < 16; ++i)
        tmp[i] = (f16)(tile[c_g + i][n_l] * rn);
    f16* dst = fnT + (size_t)(b * N + n1 + n_l) * CF + c0 + c_g;
    ((uint4*)dst)[0] = ((const uint4*)tmp)[0];
    ((uint4*)dst)[1] = ((const uint4*)tmp)[1];
}

// ---------------- MFMA GEMM: K = exp((f1 f2^T - 1)/eps) ----------------
// Writes fp32 K (scattered, into d_out T region) for the accurate final pass,
// plus (H path) a coalesced fp16 shadow Kh via LDS transpose, plus per-block
// column-sum partials (= N * (K^T a0)) into ktapG[b][blockIdx.x][...].
template<bool H>
__global__ __launch_bounds__(256) void gemm_k(const f16* __restrict__ fnT,
                                              const float* __restrict__ e_in,
                                              float* __restrict__ Kf,
                                              f16* __restrict__ Kh,
                                              float* __restrict__ ktap) {
    int b  = blockIdx.z;
    int m0 = blockIdx.y * 128;
    int n0 = blockIdx.x * 128;
    const f16* A = fnT + (size_t)b       * N * CF;   // rows n
    const f16* B = fnT + (size_t)(b + 4) * N * CF;   // rows m

    __shared__ f16 As[128 * 32];
    __shared__ f16 Bs[128 * 32];
    __shared__ float cs[2][128];
    __shared__ f16 Ct[H ? 128 * 136 : 1];   // stride 136: 16B-aligned rows

    int tid = threadIdx.x;
    int w = tid >> 6;        // wave 0..3
    int l = tid & 63;        // lane
    int wr = w >> 1, wc = w & 1;

    f32x4 acc[4][4];
    #pragma unroll
    for (int i = 0; i < 4; ++i)
        #pragma unroll
        for (int j = 0; j < 4; ++j)
            acc[i][j] = (f32x4){0.f, 0.f, 0.f, 0.f};

    int srow = l >> 2;       // 0..15 within chunk
    int scp  = l & 3;        // stored chunk index c'

    for (int c0 = 0; c0 < CF; c0 += 32) {
        #pragma unroll
        for (int q = 0; q < 2; ++q) {
            int ch = w * 2 + q;          // 0..7
            int row = ch * 16 + srow;    // 0..127
            int cc = scp ^ ((row >> 1) & 3);
            async_copy16(&As[ch * 512], A + (size_t)(n0 + row) * CF + c0 + cc * 8);
            async_copy16(&Bs[ch * 512], B + (size_t)(m0 + row) * CF + c0 + cc * 8);
        }
        __syncthreads();

        f16x8 af[4], bfr[4];
        int g = l >> 4, low = l & 15;
        #pragma unroll
        for (int t = 0; t < 4; ++t) {
            int rowA = wr * 64 + t * 16 + low;
            af[t] = *(const f16x8*)(As + rowA * 32 + (g ^ ((rowA >> 1) & 3)) * 8);
            int rowB = wc * 64 + t * 16 + low;
            bfr[t] = *(const f16x8*)(Bs + rowB * 32 + (g ^ ((rowB >> 1) & 3)) * 8);
        }
        #pragma unroll
        for (int i = 0; i < 4; ++i)
            #pragma unroll
            for (int j = 0; j < 4; ++j)
                acc[i][j] = __builtin_amdgcn_mfma_f32_16x16x32_f16(af[i], bfr[j], acc[i][j], 0, 0, 0);
        __syncthreads();
    }

    float eps = expf(e_in[0]) + 0.03f;
    float inv_eps = 1.0f / eps;
    int g4 = l >> 4, low = l & 15;
    float colp[4] = {0.f, 0.f, 0.f, 0.f};
    float* out = Kf + (size_t)b * N * N;

    #pragma unroll
    for (int i = 0; i < 4; ++i) {
        int rl = wr * 64 + i * 16 + g4 * 4;
        #pragma unroll
        for (int j = 0; j < 4; ++j) {
            int cl = wc * 64 + j * 16 + low;
            #pragma unroll
            for (int r = 0; r < 4; ++r) {
                float v = expf((acc[i][j][r] - 1.0f) * inv_eps);
                out[(size_t)(n0 + rl + r) * N + m0 + cl] = v;
                if constexpr (H) Ct[(rl + r) * 136 + cl] = (f16)v;
                colp[j] += v;
            }
        }
    }

    // reduce column partials across g (lanes l, l+16, l+32, l+48 share a column)
    #pragma unroll
    for (int j = 0; j < 4; ++j) {
        float c = colp[j];
        c += __shfl_down(c, 32);
        c += __shfl_down(c, 16);
        if (l < 16) cs[wr][wc * 64 + j * 16 + l] = c;
    }
    __syncthreads();
    if (tid < 128)
        ktap[((size_t)b * 64 + blockIdx.x) * N + m0 + tid] =
            (cs[0][tid] + cs[1][tid]) * (1.0f / N);

    if constexpr (H) {
        f16* oh = Kh + (size_t)b * N * N;
        int row0 = tid >> 4, c8 = (tid & 15) * 8;
        #pragma unroll
        for (int rr = 0; rr < 8; ++rr) {
            int row = rr * 16 + row0;
            f16x8 v = *(const f16x8*)(Ct + row * 136 + c8);
            *(f16x8*)(oh + (size_t)(n0 + row) * N + m0 + c8) = v;
        }
    }
}

// ---------------- b[m] = (prob2/(KTa[m]+1e-8))^power ----------------
// KTa summed from npart slot-major partials; block = 64 cols x 4 partial-groups.
__global__ __launch_bounds__(256) void bvec_kernel(const float* __restrict__ ktap,
                                                   int npart, int slotstride,
                                                   const float* __restrict__ g_in,
                                                   const float* __restrict__ e_in,
                                                   float* __restrict__ bvec) {
    int cl = threadIdx.x & 63;
    int pg = threadIdx.x >> 6;             // 0..3
    int i = blockIdx.x * 64 + cl;          // 0..NB*N-1
    int b = i >> 12, m = i & (N - 1);
    const float* p = ktap + (size_t)b * slotstride * N + m;
    int per = npart >> 2;
    float s = 0.f;
    #pragma unroll 8
    for (int k = pg * per; k < (pg + 1) * per; ++k) s += p[(size_t)k * N];
    __shared__ float sh[4][64];
    sh[pg][cl] = s; __syncthreads();
    if (threadIdx.x < 64) {
        float tot = sh[0][cl] + sh[1][cl] + sh[2][cl] + sh[3][cl];
        float eps = expf(e_in[0]) + 0.03f;
        float gam = expf(g_in[0]);
        float power = gam / (gam + eps);
        bvec[i] = powf((1.0f / N) / (tot + 1e-8f), power);
    }
}

// ---------------- fused: Kb -> a (in-block), then partial K^T a  ----------------
// One HBM pass over K per Sinkhorn iteration. Slab = 16 rows -> grid (256, NB)
// = 1024 blocks = 4 blocks/CU = 16 waves/CU (was 1 wave/SIMD -> no latency hiding).
// Phase 2 re-reads the 128KB slab (L2/L3-hot).
template<bool H>
__global__ __launch_bounds__(256) void fused_iter(const void* __restrict__ Kp,
                                                  const float* __restrict__ bv_in,
                                                  const float* __restrict__ g_in,
                                                  const float* __restrict__ e_in,
                                                  float* __restrict__ ktap) {
    int b = blockIdx.y, slab = blockIdx.x;      // slab 0..255
    int n0s = slab * 16;
    int w = threadIdx.x >> 6, l = threadIdx.x & 63;
    __shared__ float ash[16];
    float eps = expf(e_in[0]) + 0.03f;
    float gam = expf(g_in[0]);
    float power = gam / (gam + eps);
    const float* bv = bv_in + b * N;

    float acc[4] = {0.f, 0.f, 0.f, 0.f};

    // phase 1: wave w handles rows w*4 .. w*4+3
    if constexpr (H) {
        const f16* Kb = (const f16*)Kp + ((size_t)b * N + n0s) * N;
        for (int it = 0; it < 8; ++it) {
            int m = it * 512 + l * 8;
            float bq[8];
            *(float4*)&bq[0] = *(const float4*)(bv + m);
            *(float4*)&bq[4] = *(const float4*)(bv + m + 4);
            #pragma unroll
            for (int rr = 0; rr < 4; ++rr) {
                f16x8 v = *(const f16x8*)(Kb + (size_t)(w * 4 + rr) * N + m);
                #pragma unroll
                for (int q = 0; q < 8; ++q) acc[rr] = fmaf((float)v[q], bq[q], acc[rr]);
            }
        }
    } else {
        const float* Kb = (const float*)Kp + ((size_t)b * N + n0s) * N;
        for (int it = 0; it < 16; ++it) {
            int m = it * 256 + l * 4;
            float4 bq = *(const float4*)(bv + m);
            #pragma unroll
            for (int rr = 0; rr < 4; ++rr) {
                float4 v = *(const float4*)(Kb + (size_t)(rr * 4 + w) * N + m);
                acc[rr] = fmaf(v.x, bq.x, acc[rr]);
                acc[rr] = fmaf(v.y, bq.y, acc[rr]);
                acc[rr] = fmaf(v.z, bq.z, acc[rr]);
                acc[rr] = fmaf(v.w, bq.w, acc[rr]);
            }
        }
    }
    #pragma unroll
    for (int rr = 0; rr < 4; ++rr) {
        float s = acc[rr];
        s += __shfl_down(s, 32);
        s += __shfl_down(s, 16);
        s += __shfl_down(s, 8);
        s += __shfl_down(s, 4);
        s += __shfl_down(s, 2);
        s += __shfl_down(s, 1);
        if (l == 0) ash[(H ? w * 4 + rr : rr * 4 + w)] =
            powf((1.0f / N) / (s + 1e-8f), power);
    }
    __syncthreads();

    // phase 2: partial K^T a over this slab; thread owns cols {t*4..t*4+3 + q*1024}
    float cacc[16];
    #pragma unroll
    for (int q = 0; q < 16; ++q) cacc[q] = 0.f;
    int t4 = threadIdx.x * 4;
    if constexpr (H) {
        const f16* Kb = (const f16*)Kp + ((size_t)b * N + n0s) * N;
        for (int r = 0; r < 16; ++r) {
            float a = ash[r];
            #pragma unroll
            for (int q = 0; q < 4; ++q) {
                f16x4 v = *(const f16x4*)(Kb + (size_t)r * N + q * 1024 + t4);
                #pragma unroll
                for (int j = 0; j < 4; ++j)
                    cacc[q * 4 + j] = fmaf((float)v[j], a, cacc[q * 4 + j]);
            }
        }
    } else {
        const float* Kb = (const float*)Kp + ((size_t)b * N + n0s) * N;
        for (int r = 0; r < 16; ++r) {
            float a = ash[r];
            #pragma unroll
            for (int q = 0; q < 4; ++q) {
                float4 v = *(const float4*)(Kb + (size_t)r * N + q * 1024 + t4);
                cacc[q * 4 + 0] = fmaf(v.x, a, cacc[q * 4 + 0]);
                cacc[q * 4 + 1] = fmaf(v.y, a, cacc[q * 4 + 1]);
                cacc[q * 4 + 2] = fmaf(v.z, a, cacc[q * 4 + 2]);
                cacc[q * 4 + 3] = fmaf(v.w, a, cacc[q * 4 + 3]);
            }
        }
    }
    float* o = ktap + ((size_t)b * 256 + slab) * N;
    #pragma unroll
    for (int q = 0; q < 4; ++q)
        *(float4*)(o + q * 1024 + t4) =
            make_float4(cacc[q * 4], cacc[q * 4 + 1], cacc[q * 4 + 2], cacc[q * 4 + 3]);
}

// ---------------- final: a5 = g(K b5) in-block from fp32 K; T = a K b^T in place ----
__global__ __launch_bounds__(256) void final_k(float* __restrict__ Tout,
                                               const float* __restrict__ bv_in,
                                               const float* __restrict__ g_in,
                                               const float* __restrict__ e_in,
                                               const float* __restrict__ pc,
                                               float* __restrict__ rowsum,
                                               float* __restrict__ matches) {
    int b = blockIdx.y, n = blockIdx.x;
    int t = threadIdx.x;
    int t4 = t * 4;
    const float* bv = bv_in + b * N;
    float kv[16], bl[16];
    float* Trow = Tout + ((size_t)b * N + n) * N;
    #pragma unroll
    for (int q = 0; q < 4; ++q) {
        *(float4*)&bl[q * 4] = *(const float4*)(bv + q * 1024 + t4);
        *(float4*)&kv[q * 4] = *(const float4*)(Trow + q * 1024 + t4);
    }
    float s = 0.f;
    #pragma unroll
    for (int q = 0; q < 16; ++q) s = fmaf(kv[q], bl[q], s);
    __shared__ float red[256];
    red[t] = s; __syncthreads();
    for (int off = 128; off; off >>= 1) {
        if (t < off) red[t] += red[t + off];
        __syncthreads();
    }
    __shared__ float a_sh;
    if (t == 0) {
        float eps = expf(e_in[0]) + 0.03f;
        float gam = expf(g_in[0]);
        float power = gam / (gam + eps);
        a_sh = powf((1.0f / N) / (red[0] + 1e-8f), power);
    }
    __syncthreads();
    float an = a_sh;
    const float4* c2 = (const float4*)pc + (size_t)(4 + b) * N;
    float rs = 0.f, s0 = 0.f, s1 = 0.f, s2 = 0.f;
    #pragma unroll
    for (int q = 0; q < 4; ++q) {
        float tv0 = an * kv[q * 4 + 0] * bl[q * 4 + 0];
        float tv1 = an * kv[q * 4 + 1] * bl[q * 4 + 1];
        float tv2 = an * kv[q * 4 + 2] * bl[q * 4 + 2];
        float tv3 = an * kv[q * 4 + 3] * bl[q * 4 + 3];
        *(float4*)(Trow + q * 1024 + t4) = make_float4(tv0, tv1, tv2, tv3);
        rs += tv0 + tv1 + tv2 + tv3;
        float4 c0 = c2[q * 1024 + t4],     c1 = c2[q * 1024 + t4 + 1],
               cc = c2[q * 1024 + t4 + 2], c3 = c2[q * 1024 + t4 + 3];
        s0 = fmaf(tv0, c0.y, s0); s1 = fmaf(tv0, c0.z, s1); s2 = fmaf(tv0, c0.w, s2);
        s0 = fmaf(tv1, c1.y, s0); s1 = fmaf(tv1, c1.z, s1); s2 = fmaf(tv1, c1.w, s2);
        s0 = fmaf(tv2, cc.y, s0); s1 = fmaf(tv2, cc.z, s1); s2 = fmaf(tv2, cc.w, s2);
        s0 = fmaf(tv3, c3.y, s0); s1 = fmaf(tv3, c3.z, s1); s2 = fmaf(tv3, c3.w, s2);
    }
    __shared__ float4 red4[256];
    red4[t] = make_float4(rs, s0, s1, s2); __syncthreads();
    for (int off = 128; off; off >>= 1) {
        if (t < off) {
            float4 o = red4[t + off];
            red4[t].x += o.x; red4[t].y += o.y; red4[t].z += o.z; red4[t].w += o.w;
        }
        __syncthreads();
    }
    if (t == 0) {
        float4 tot = red4[0];
        rowsum[b * N + n] = tot.x;
        float inv = 1.0f / (tot.x + 1e-8f);
        float* mo = matches + ((size_t)b * N + n) * 3;
        mo[0] = tot.y * inv; mo[1] = tot.z * inv; mo[2] = tot.w * inv;
    }
}

// ---------------- weighted Kabsch with 3x3 SVD (fp64) ----------------
__global__ __launch_bounds__(256) void transform_kernel(const float* __restrict__ rowsum,
                                                        const float* __restrict__ matches,
                                                        const float* __restrict__ pc,
                                                        float* __restrict__ out) {
    int b = blockIdx.x;
    float vals[16];
    #pragma unroll
    for (int q = 0; q < 16; ++q) vals[q] = 0.f;
    for (int n = threadIdx.x; n < N; n += 256) {
        float w = rowsum[b * N + n];
        float4 c1 = ((const float4*)pc)[(size_t)b * N + n];
        float ax = c1.y, ay = c1.z, az = c1.w;
        const float* mm = matches + ((size_t)b * N + n) * 3;
        float bx = mm[0], by = mm[1], bz = mm[2];
        vals[0] += w;
        vals[1] = fmaf(w, ax, vals[1]); vals[2] = fmaf(w, ay, vals[2]); vals[3] = fmaf(w, az, vals[3]);
        vals[4] = fmaf(w, bx, vals[4]); vals[5] = fmaf(w, by, vals[5]); vals[6] = fmaf(w, bz, vals[6]);
        vals[7]  = fmaf(w * ax, bx, vals[7]);  vals[8]  = fmaf(w * ax, by, vals[8]);  vals[9]  = fmaf(w * ax, bz, vals[9]);
        vals[10] = fmaf(w * ay, bx, vals[10]); vals[11] = fmaf(w * ay, by, vals[11]); vals[12] = fmaf(w * ay, bz, vals[12]);
        vals[13] = fmaf(w * az, bx, vals[13]); vals[14] = fmaf(w * az, by, vals[14]); vals[15] = fmaf(w * az, bz, vals[15]);
    }
    __shared__ float red[256];
    __shared__ float tot[16];
    for (int q = 0; q < 16; ++q) {
        red[threadIdx.x] = vals[q]; __syncthreads();
        for (int off = 128; off; off >>= 1) {
            if (threadIdx.x < off) red[threadIdx.x] += red[threadIdx.x + off];
            __syncthreads();
        }
        if (threadIdx.x == 0) tot[q] = red[0];
        __syncthreads();
    }
    if (threadIdx.x != 0) return;

    double S = tot[0];
    double denom = S + 1e-5;
    double Ca[3], Cb[3], M[3][3], cov[3][3];
    for (int i = 0; i < 3; ++i) { Ca[i] = tot[1 + i] / denom; Cb[i] = tot[4 + i] / denom; }
    for (int i = 0; i < 3; ++i)
        for (int j = 0; j < 3; ++j)
            M[i][j] = tot[7 + i * 3 + j] / denom;
    double s0 = S / denom;
    for (int i = 0; i < 3; ++i)
        for (int j = 0; j < 3; ++j)
            cov[i][j] = M[i][j] - Ca[i] * Cb[j] * (2.0 - s0);

    double Sm[3][3], V[3][3] = {{1,0,0},{0,1,0},{0,0,1}};
    for (int i = 0; i < 3; ++i)
        for (int j = 0; j < 3; ++j) {
            double acc = 0;
            for (int k = 0; k < 3; ++k) acc += cov[k][i] * cov[k][j];
            Sm[i][j] = acc;
        }
    for (int sweep = 0; sweep < 20; ++sweep) {
        static const int pq[3][2] = {{0,1},{0,2},{1,2}};
        for (int r = 0; r < 3; ++r) {
            int p = pq[r][0], q = pq[r][1];
            double apq = Sm[p][q];
            if (fabs(apq) < 1e-30) continue;
            double tau = (Sm[q][q] - Sm[p][p]) / (2.0 * apq);
            double t = (tau >= 0) ? 1.0 / (tau + sqrt(1.0 + tau * tau))
                                  : 1.0 / (tau - sqrt(1.0 + tau * tau));
            double c = 1.0 / sqrt(1.0 + t * t), s = t * c;
            for (int i = 0; i < 3; ++i) {
                double sip = Sm[i][p], siq = Sm[i][q];
                Sm[i][p] = c * sip - s * siq; Sm[i][q] = s * sip + c * siq;
            }
            for (int j = 0; j < 3; ++j) {
                double spj = Sm[p][j], sqj = Sm[q][j];
                Sm[p][j] = c * spj - s * sqj; Sm[q][j] = s * spj + c * sqj;
            }
            for (int i = 0; i < 3; ++i) {
                double vip = V[i][p], viq = V[i][q];
                V[i][p] = c * vip - s * viq; V[i][q] = s * vip + c * viq;
            }
        }
    }
    double lam[3] = {Sm[0][0], Sm[1][1], Sm[2][2]};
    for (int i = 0; i < 2; ++i)
        for (int j = i + 1; j < 3; ++j)
            if (lam[j] > lam[i]) {
                double tl = lam[i]; lam[i] = lam[j]; lam[j] = tl;
                for (int k = 0; k < 3; ++k) { double tv = V[k][i]; V[k][i] = V[k][j]; V[k][j] = tv; }
            }
    double U[3][3];
    double sig0 = sqrt(fmax(lam[0], 0.0));
    for (int j = 0; j < 3; ++j) {
        double sig = sqrt(fmax(lam[j], 0.0));
        if (sig > 1e-12 * (sig0 + 1e-300)) {
            double nrm = 0;
            for (int i = 0; i < 3; ++i) {
                double u = cov[i][0] * V[0][j] + cov[i][1] * V[1][j] + cov[i][2] * V[2][j];
                U[i][j] = u; nrm += u * u;
            }
            nrm = 1.0 / sqrt(nrm + 1e-300);
            for (int i = 0; i < 3; ++i) U[i][j] *= nrm;
        } else {
            U[0][j] = U[1][0] * U[2][1] - U[2][0] * U[1][1];
            U[1][j] = U[2][0] * U[0][1] - U[0][0] * U[2][1];
            U[2][j] = U[0][0] * U[1][1] - U[1][0] * U[0][1];
        }
    }
    double R[3][3];
    for (int i = 0; i < 3; ++i)
        for (int j = 0; j < 3; ++j)
            R[i][j] = V[i][0] * U[j][0] + V[i][1] * U[j][1] + V[i][2] * U[j][2];
    double det = R[0][0] * (R[1][1] * R[2][2] - R[1][2] * R[2][1])
               - R[0][1] * (R[1][0] * R[2][2] - R[1][2] * R[2][0])
               + R[0][2] * (R[1][0] * R[2][1] - R[1][1] * R[2][0]);
    if (!(det > 0)) {
        for (int k = 0; k < 3; ++k) V[k][2] = -V[k][2];
        for (int i = 0; i < 3; ++i)
            for (int j = 0; j < 3; ++j)
                R[i][j] = V[i][0] * U[j][0] + V[i][1] * U[j][1] + V[i][2] * U[j][2];
    }
    double tr[3];
    for (int i = 0; i < 3; ++i)
        tr[i] = -(R[i][0] * Ca[0] + R[i][1] * Ca[1] + R[i][2] * Ca[2]) + Cb[i];
    float* o = out + b * 12;
    for (int i = 0; i < 3; ++i) {
        o[i * 4 + 0] = (float)R[i][0];
        o[i * 4 + 1] = (float)R[i][1];
        o[i * 4 + 2] = (float)R[i][2];
        o[i * 4 + 3] = (float)tr[i];
    }
}

extern "C" void kernel_launch(void* const* d_in, const int* in_sizes, int n_in,
                              void* d_out, int out_size, void* d_ws, size_t ws_size,
                              hipStream_t stream) {
    const float* pf   = (const float*)d_in[0];
    const float* pc   = (const float*)d_in[1];
    const float* g_in = (const float*)d_in[2];
    const float* e_in = (const float*)d_in[3];

    char* wsb = (char*)d_ws;
    f16*   fnT   = (f16*)(wsb + OFF_FNT);
    float* rnorm = (float*)(wsb + OFF_RNORM);
    float* bvec  = (float*)(wsb + OFF_BVEC);

    float* T_out   = (float*)d_out;
    float* matches = T_out + (size_t)NB * N * N;
    float* trans   = matches + (size_t)NB * N * 3;
    // rnorm consumed by transpose_kernel before final_k runs -> safe alias
    float* rowsum  = rnorm;

    rnorm_kernel<<<dim3(8 * N / 256), 256, 0, stream>>>(pf, rnorm);
    transpose_kernel<<<dim3(CF / 64, N / 64, 8), 256, 0, stream>>>(pf, rnorm, fnT);

    // fused_iter partials reuse the fnT region (dead after gemm_k)
    float* ktapF = (float*)(wsb + OFF_FNT);

    if (ws_size >= (size_t)REQ_H) {
        // fp32 K in d_out T region (for accurate final), fp16 shadow for Sinkhorn.
        f16*   Kh    = (f16*)(wsb + OFF_SCR);
        float* ktapG = (float*)(wsb + OFF_KTAP);
        gemm_k<true><<<dim3(N / 128, N / 128, NB), 256, 0, stream>>>(fnT, e_in, T_out, Kh, ktapG);
        bvec_kernel<<<dim3(NB * N / 64), 256, 0, stream>>>(ktapG, 32, 64, g_in, e_in, bvec);
        for (int it = 0; it < 4; ++it) {
            fused_iter<true><<<dim3(N / 16, NB), 256, 0, stream>>>(Kh, bvec, g_in, e_in, ktapF);
            bvec_kernel<<<dim3(NB * N / 64), 256, 0, stream>>>(ktapF, 256, 256, g_in, e_in, bvec);
        }
        final_k<<<dim3(N, NB), 256, 0, stream>>>(T_out, bvec, g_in, e_in, pc, rowsum, matches);
    } else {
        // fallback: fp32 K everywhere (Sinkhorn reads fp32 K from T region)
        float* ktapG = (float*)(wsb + OFF_SCR);
        gemm_k<false><<<dim3(N / 128, N / 128, NB), 256, 0, stream>>>(fnT, e_in, T_out, (f16*)nullptr, ktapG);
        bvec_kernel<<<dim3(NB * N / 64), 256, 0, stream>>>(ktapG, 32, 64, g_in, e_in, bvec);
        for (int it = 0; it < 4; ++it) {
            fused_iter<false><<<dim3(N / 16, NB), 256, 0, stream>>>(T_out, bvec, g_in, e_in, ktapF);
            bvec_kernel<<<dim3(NB * N / 64), 256, 0, stream>>>(ktapF, 256, 256, g_in, e_in, bvec);
        }
        final_k<<<dim3(N, NB), 256, 0, stream>>>(T_out, bvec, g_in, e_in, pc, rowsum, matches);
    }

    transform_kernel<<<dim3(NB), 256, 0, stream>>>(rowsum, matches, pc, trans);
}